// Round 6
// baseline (701.962 us; speedup 1.0000x reference)
//
#include <hip/hip_runtime.h>

// Problem constants
#define B_     2
#define P_TOT  4000
#define NP_TOT 4096
#define D_     64
#define M_     512
#define HW_TOT 214272   // 496*432
#define J4     53568    // HW/4

// Output offsets (in floats, concatenated return order)
#define O0 0UL            // spatial_features        [2,128,HW]
#define O1 54853632UL     // spatial_features_point  [2,128,HW]
#define O2 109707264UL    // spatial_scale_features  [2,64,HW]
#define O3 137134080UL    // point_positive_features [8000,64]
#define O4 137646080UL    // memory_positive_features[8000,64]

typedef __attribute__((ext_vector_type(8))) short bb8;
typedef __attribute__((ext_vector_type(4))) float f32x4;

__device__ __forceinline__ void fma4(float4& a, const float4& x, const float4& y) {
  a.x = fmaf(x.x, y.x, a.x);
  a.y = fmaf(x.y, y.y, a.y);
  a.z = fmaf(x.z, y.z, a.z);
  a.w = fmaf(x.w, y.w, a.w);
}

// Sorted-descending insert into top-8 registers (caller guards with sc > s[7])
__device__ __forceinline__ void insert8(float sc, int n, float s[8], int ix[8]) {
  float cs = sc; int ci = n;
#pragma unroll
  for (int i = 0; i < 8; ++i) {
    bool gt = cs > s[i];
    float ts = s[i]; int ti = ix[i];
    s[i]  = gt ? cs : ts;  ix[i] = gt ? ci : ti;
    cs    = gt ? ts : cs;  ci    = gt ? ti : ci;
  }
}

__device__ __forceinline__ void split_bf16(float x, short& h, short& l) {
  unsigned fb = __float_as_uint(x);
  unsigned hb = fb & 0xFFFF0000u;          // truncate to bf16 (hi plane)
  float lof = x - __uint_as_float(hb);     // residual
  h = (short)(hb >> 16);
  l = (short)(__float_as_uint(lof) >> 16); // bf16 of residual (lo plane)
}

// prep: fused [cvt_planes (blocks 0..511)] + [build_owner (blocks 512..543)].
// cvt arithmetic FROZEN since R2.
__global__ __launch_bounds__(256) void prep(
    const float* __restrict__ points, short* __restrict__ hi, short* __restrict__ lo,
    const int* __restrict__ indices, int* __restrict__ owner)
{
  if (blockIdx.x < 512) {
    int t = blockIdx.x * 256 + threadIdx.x;           // n4 = 131072 exactly
    float4 v = ((const float4*)points)[t];
    float x[4] = {v.x, v.y, v.z, v.w};
    short h[4], l[4];
#pragma unroll
    for (int j = 0; j < 4; ++j) split_bf16(x[j], h[j], l[j]);
    ((short4*)hi)[t] = make_short4(h[0], h[1], h[2], h[3]);
    ((short4*)lo)[t] = make_short4(l[0], l[1], l[2], l[3]);
  } else {
    int t = (blockIdx.x - 512) * 256 + threadIdx.x;
    if (t >= B_ * P_TOT) return;
    int b = (t >= P_TOT) ? 1 : 0;
    int p = t - b * P_TOT;
    atomicMax(&owner[b * HW_TOT + indices[t]], p);
  }
}

// R6: merged top-k kernel. Blocks [0,1008): MFMA points branch (was topk_mfma,
// grid 63x8x2). Blocks [1008,3008): VALU memory branch (was topk_chunk, grid
// 125x8x2, src=W, stride 0, n_tiles=1). All selection/scoring arithmetic is
// FROZEN (bit-identical to R5); only block->work mapping and LDS placement
// changed. Mem path's merge buffer aliases the staging buffer (first use is
// after the staging loop's final __syncthreads) to keep LDS at 24.8 KB so the
// MFMA path's occupancy stays VGPR-limited, not LDS-limited.
__global__ __launch_bounds__(256) void topk_all(
    const float* __restrict__ pillars,
    const short* __restrict__ phi, const short* __restrict__ plo,
    const float* __restrict__ W,
    float* __restrict__ ws_pts_sc, int* __restrict__ ws_pts_ix,
    float* __restrict__ ws_mem_sc, int* __restrict__ ws_mem_ix)
{
  __shared__ float lds_pts[4224];   // mem path: staging [0,4096), then cs merge [0,2080)
  __shared__ int   ci_lds[2080];

  const int tid = threadIdx.x;

  if (blockIdx.x < 1008) {
    // ---------------- MFMA points branch ----------------
    const unsigned u = blockIdx.x;
    const int pt = u % 63, ch = (u / 63) % 8, b = u / 504;
    const int lane = tid & 63, wv = tid >> 6;
    const int sub = lane & 15, quad = lane >> 4;

    int prow = pt * 64 + wv * 16 + sub;
    if (prow >= P_TOT) prow = P_TOT - 1;
    const float* ap = pillars + ((size_t)(b * P_TOT) + prow) * D_;
    bb8 Ah0, Ah1, Al0, Al1;
    {
      const float4* a4 = (const float4*)(ap + quad * 8);
      const float4* b4 = (const float4*)(ap + 32 + quad * 8);
      float4 t0 = a4[0], t1 = a4[1], t2 = b4[0], t3 = b4[1];
      float av[16] = {t0.x, t0.y, t0.z, t0.w, t1.x, t1.y, t1.z, t1.w,
                      t2.x, t2.y, t2.z, t2.w, t3.x, t3.y, t3.z, t3.w};
#pragma unroll
      for (int j = 0; j < 8; ++j) {
        short h, l;
        split_bf16(av[j], h, l);     Ah0[j] = h; Al0[j] = l;
        split_bf16(av[8 + j], h, l); Ah1[j] = h; Al1[j] = l;
      }
    }

    float sv[4][8]; int iv[4][8];
#pragma unroll
    for (int r = 0; r < 4; ++r)
#pragma unroll
      for (int k = 0; k < 8; ++k) { sv[r][k] = -1e30f; iv[r][k] = 0; }

    const size_t bofs = ((size_t)(b * NP_TOT) + ch * 512) * D_;
    const short* bh = phi + bofs;
    const short* bl = plo + bofs;

#pragma unroll 2
    for (int it = 0; it < 32; ++it) {
      const int nr = it * 16 + sub;
      const short* rh = bh + nr * D_;
      const short* rl = bl + nr * D_;
      bb8 Bh0 = *(const bb8*)(rh + quad * 8);
      bb8 Bh1 = *(const bb8*)(rh + 32 + quad * 8);
      bb8 Bl0 = *(const bb8*)(rl + quad * 8);
      bb8 Bl1 = *(const bb8*)(rl + 32 + quad * 8);
      f32x4 acc = {0.f, 0.f, 0.f, 0.f};
      acc = __builtin_amdgcn_mfma_f32_16x16x32_bf16(Al0, Bh0, acc, 0, 0, 0);
      acc = __builtin_amdgcn_mfma_f32_16x16x32_bf16(Al1, Bh1, acc, 0, 0, 0);
      acc = __builtin_amdgcn_mfma_f32_16x16x32_bf16(Ah0, Bl0, acc, 0, 0, 0);
      acc = __builtin_amdgcn_mfma_f32_16x16x32_bf16(Ah1, Bl1, acc, 0, 0, 0);
      acc = __builtin_amdgcn_mfma_f32_16x16x32_bf16(Ah0, Bh0, acc, 0, 0, 0);
      acc = __builtin_amdgcn_mfma_f32_16x16x32_bf16(Ah1, Bh1, acc, 0, 0, 0);
      const int ng = ch * 512 + nr;
#pragma unroll
      for (int r = 0; r < 4; ++r) {
        float sc = acc[r];
        if (sc > sv[r][7]) insert8(sc, ng, sv[r], iv[r]);
      }
    }

    const int pbase = pt * 64 + wv * 16 + quad * 4;
#pragma unroll
    for (int r = 0; r < 4; ++r) {
      const int pg = pbase + r;
      float out_s = 0.f; int out_i = 0;
#pragma unroll
      for (int k = 0; k < 8; ++k) {
        unsigned fb = __float_as_uint(sv[r][0]);
        unsigned mk = (fb & 0x80000000u) ? ~fb : (fb | 0x80000000u);
        unsigned key = (mk & 0xFFFFFFF0u) | (unsigned)sub;
#pragma unroll
        for (int off = 1; off < 16; off <<= 1) {
          unsigned ok = (unsigned)__shfl_xor((int)key, off);
          key = key > ok ? key : ok;
        }
        const int wsub = (int)(key & 15u);
        const int wlane = (lane & 48) | wsub;
        float wsc = __shfl(sv[r][0], wlane);
        int   wix = __shfl(iv[r][0], wlane);
        if (sub == wsub) {
#pragma unroll
          for (int i2 = 0; i2 < 7; ++i2) { sv[r][i2] = sv[r][i2 + 1]; iv[r][i2] = iv[r][i2 + 1]; }
          sv[r][7] = -1e30f;
        }
        if (sub == k) { out_s = wsc; out_i = wix; }
      }
      if (sub < 8 && pg < P_TOT) {
        const size_t base = ((size_t)(b * P_TOT) + pg) * 64 + ch * 8 + sub;
        ws_pts_sc[base] = out_s; ws_pts_ix[base] = out_i;
      }
    }
  } else {
    // ---------------- VALU memory branch (src = W, n_tiles = 1) ----------------
    const unsigned u = blockIdx.x - 1008;
    const int pt = u % 125, ch = (u / 125) % 8, b = u / 1000;
    const int pp = tid & 31, sg = tid >> 5;
    const int p = pt * 32 + pp;

    const float4* prow = (const float4*)(pillars + ((size_t)(b * P_TOT + p)) * D_);
    float4 pl[16];
#pragma unroll
    for (int i = 0; i < 16; ++i) pl[i] = prow[i];

    float s[8]; int ix[8];
#pragma unroll
    for (int i = 0; i < 8; ++i) { s[i] = -1e30f; ix[i] = 0; }

    const int n_base = ch * 64;
    const int r0 = tid >> 2, seg = tid & 3;

    {
      const float4* g = (const float4*)(W + ((size_t)(n_base + r0)) * D_ + seg * 16);
      float4* dst4 = (float4*)(lds_pts + r0 * 64 + seg * 16);
      dst4[0] = g[0]; dst4[1] = g[1]; dst4[2] = g[2]; dst4[3] = g[3];
      __syncthreads();

#pragma unroll
      for (int r = 0; r < 8; ++r) {
        const int row = sg * 8 + r;
        const float4* q = (const float4*)(lds_pts + row * 64);
        float4 a0 = {0,0,0,0}, a1 = {0,0,0,0}, a2 = {0,0,0,0}, a3 = {0,0,0,0};
#pragma unroll
        for (int i = 0; i < 4; ++i) {
          fma4(a0, pl[i*4+0], q[i*4+0]);
          fma4(a1, pl[i*4+1], q[i*4+1]);
          fma4(a2, pl[i*4+2], q[i*4+2]);
          fma4(a3, pl[i*4+3], q[i*4+3]);
        }
        float sc = ((a0.x + a1.x) + (a2.x + a3.x)) + ((a0.y + a1.y) + (a2.y + a3.y))
                 + ((a0.z + a1.z) + (a2.z + a3.z)) + ((a0.w + a1.w) + (a2.w + a3.w));
        int n = n_base + row;
        if (sc > s[7]) insert8(sc, n, s, ix);
      }
      __syncthreads();
    }

    // merge buffer aliases the (now dead) staging buffer
    float* cs_lds = lds_pts;
#pragma unroll
    for (int k = 0; k < 8; ++k) {
      cs_lds[pp * 65 + sg * 8 + k] = s[k];
      ci_lds[pp * 65 + sg * 8 + k] = ix[k];
    }
    __syncthreads();
    if (tid < 32) {
      float ms[8]; int mi[8];
#pragma unroll
      for (int i = 0; i < 8; ++i) { ms[i] = -1e30f; mi[i] = 0; }
      for (int k = 0; k < 64; ++k) {
        float sc = cs_lds[tid * 65 + k];
        int   ii = ci_lds[tid * 65 + k];
        if (sc > ms[7]) insert8(sc, ii, ms, mi);
      }
      const int p2 = pt * 32 + tid;
      size_t base = ((size_t)(b * P_TOT + p2)) * 64 + ch * 8;
#pragma unroll
      for (int k = 0; k < 8; ++k) { ws_mem_sc[base + k] = ms[k]; ws_mem_ix[base + k] = mi[k]; }
    }
  }
}

// Merged finalize: grid.y = 0 -> points branch, 1 -> memory branch.
// Per-branch arithmetic FROZEN since R1.
__global__ __launch_bounds__(256) void finalize2(
    const float* __restrict__ points, const float* __restrict__ W,
    const float* __restrict__ ws_sc_p, const int* __restrict__ ws_ix_p,
    const float* __restrict__ ws_sc_m, const int* __restrict__ ws_ix_m,
    float* __restrict__ out_p, float* __restrict__ out_m)
{
  const int tid = threadIdx.x;
  const int lane = tid & 63, wv = tid >> 6;
  const int gp = blockIdx.x * 4 + wv;
  const int b = (gp >= P_TOT) ? 1 : 0;
  const size_t cb = (size_t)gp * 64;
  const bool mem = (blockIdx.y == 1);

  const float* ws_sc = mem ? ws_sc_m : ws_sc_p;
  const int*   ws_ix = mem ? ws_ix_m : ws_ix_p;
  const float* sb    = mem ? W : (points + (size_t)b * (NP_TOT * D_));
  float*       outp  = mem ? out_m : out_p;

  float ss = ws_sc[cb + lane];
  const int myix = ws_ix[cb + lane];

  float wsc[8]; int wix[8];
#pragma unroll
  for (int k = 0; k < 8; ++k) {
    float cv = ss; int cl = lane;
#pragma unroll
    for (int off = 32; off >= 1; off >>= 1) {
      float ov = __shfl_xor(cv, off);
      int   ol = __shfl_xor(cl, off);
      if (ov > cv || (ov == cv && ol < cl)) { cv = ov; cl = ol; }
    }
    wsc[k] = cv;
    wix[k] = __shfl(myix, cl);
    if (lane == cl) ss = -1e30f;
  }

  const float m = wsc[0];
  float e[8], Z = 0.f;
#pragma unroll
  for (int k = 0; k < 8; ++k) { e[k] = expf(wsc[k] - m); Z += e[k]; }
  const float inv = 1.0f / Z;

  float acc = 0.f;
#pragma unroll
  for (int k = 0; k < 8; ++k)
    acc = fmaf(e[k] * inv, sb[(size_t)wix[k] * 64 + lane], acc);
  outp[cb + lane] = acc;
}

// Scatter: thread owns (j4, c in [0,64)); loads owner int4 ONCE, gathers the
// 4 sources for occupied cells (pillars gather reused for both O0 and O1),
// writes 5 planes with non-temporal f32x4 stores. FROZEN since R5.
__global__ __launch_bounds__(256) void scatter5(
    const float* __restrict__ pillars, const float* __restrict__ scale,
    const float* __restrict__ pos_point, const float* __restrict__ pos_mem,
    const int* __restrict__ owner, float* __restrict__ out)
{
  const int j4 = blockIdx.x * 256 + threadIdx.x;
  if (j4 >= J4) return;
  const int c = blockIdx.y, b = blockIdx.z;

  const int4 own = ((const int4*)owner)[(size_t)b * J4 + j4];

  const size_t bo = (size_t)b * (P_TOT * D_);
  const float* sp = pillars   + bo;
  const float* sm = pos_mem   + bo;
  const float* sq = pos_point + bo;
  const float* ss = scale     + bo;

  f32x4 vp = {0.f, 0.f, 0.f, 0.f};
  f32x4 vm = vp, vq = vp, vs = vp;

  // sign bit of AND set iff all four are negative (empty) -> skip gathers
  if ((own.x & own.y & own.z & own.w) >= 0) {
    const size_t rx = (size_t)(own.x < 0 ? 0 : own.x) * 64 + c;
    const size_t ry = (size_t)(own.y < 0 ? 0 : own.y) * 64 + c;
    const size_t rz = (size_t)(own.z < 0 ? 0 : own.z) * 64 + c;
    const size_t rw = (size_t)(own.w < 0 ? 0 : own.w) * 64 + c;
    vp = (f32x4){own.x < 0 ? 0.f : sp[rx], own.y < 0 ? 0.f : sp[ry],
                 own.z < 0 ? 0.f : sp[rz], own.w < 0 ? 0.f : sp[rw]};
    vm = (f32x4){own.x < 0 ? 0.f : sm[rx], own.y < 0 ? 0.f : sm[ry],
                 own.z < 0 ? 0.f : sm[rz], own.w < 0 ? 0.f : sm[rw]};
    vq = (f32x4){own.x < 0 ? 0.f : sq[rx], own.y < 0 ? 0.f : sq[ry],
                 own.z < 0 ? 0.f : sq[rz], own.w < 0 ? 0.f : sq[rw]};
    vs = (f32x4){own.x < 0 ? 0.f : ss[rx], own.y < 0 ? 0.f : ss[ry],
                 own.z < 0 ? 0.f : ss[rz], own.w < 0 ? 0.f : ss[rw]};
  }

  f32x4* o4 = (f32x4*)out;
  __builtin_nontemporal_store(vp, o4 + (size_t)(b * 128 + c)       * J4 + j4);             // O0 pillars
  __builtin_nontemporal_store(vm, o4 + (size_t)(b * 128 + 64 + c)  * J4 + j4);             // O0 pos_mem
  __builtin_nontemporal_store(vp, o4 + 13713408UL + (size_t)(b * 128 + c)      * J4 + j4); // O1 pillars
  __builtin_nontemporal_store(vq, o4 + 13713408UL + (size_t)(b * 128 + 64 + c) * J4 + j4); // O1 pos_point
  __builtin_nontemporal_store(vs, o4 + 27426816UL + (size_t)(b * 64 + c)       * J4 + j4); // O2 scale
}

extern "C" void kernel_launch(void* const* d_in, const int* in_sizes, int n_in,
                              void* d_out, int out_size, void* d_ws, size_t ws_size,
                              hipStream_t stream) {
  const float* pillars = (const float*)d_in[0];   // [2,4000,64]
  const float* scale   = (const float*)d_in[1];   // [2,4000,64]
  const float* points  = (const float*)d_in[2];   // [2,4096,64]
  const float* W       = (const float*)d_in[3];   // [512,64]
  const int*   indices = (const int*)d_in[4];     // [2,4000]
  float* out = (float*)d_out;

  // ws layout (int units): pts cand 4x512000, owner 428544, bf16 planes
  float* ws_pts_sc = (float*)d_ws;
  int*   ws_pts_ix = (int*)d_ws + 512000;
  float* ws_mem_sc = (float*)d_ws + 1024000;
  int*   ws_mem_ix = (int*)d_ws + 1536000;
  int*   owner     = (int*)d_ws + 2048000;
  short* phi       = (short*)((int*)d_ws + 2480000);  // 524288 shorts
  short* plo       = (short*)((int*)d_ws + 2760000);  // 524288 shorts

  (void)hipMemsetAsync(owner, 0xFF, (size_t)B_ * HW_TOT * sizeof(int), stream);

  // fused cvt (512 blocks) + build_owner (32 blocks)
  prep<<<544, 256, 0, stream>>>(points, phi, plo, indices, owner);

  // merged top-k: blocks [0,1008) = MFMA points branch, [1008,3008) = memory branch
  topk_all<<<3008, 256, 0, stream>>>(
      pillars, phi, plo, W, ws_pts_sc, ws_pts_ix, ws_mem_sc, ws_mem_ix);

  // both branches' merge+softmax+gather in one launch
  finalize2<<<dim3(2000, 2), 256, 0, stream>>>(
      points, W, ws_pts_sc, ws_pts_ix, ws_mem_sc, ws_mem_ix, out + O3, out + O4);

  scatter5<<<dim3(210, 64, 2), 256, 0, stream>>>(
      pillars, scale, out + O3, out + O4, owner, out);
}

// Round 7
// 689.068 us; speedup vs baseline: 1.0187x; 1.0187x over previous
//
#include <hip/hip_runtime.h>

// Problem constants
#define B_     2
#define P_TOT  4000
#define NP_TOT 4096
#define D_     64
#define M_     512
#define HW_TOT 214272   // 496*432
#define J4     53568    // HW/4

// Output offsets (in floats, concatenated return order)
#define O0 0UL            // spatial_features        [2,128,HW]
#define O1 54853632UL     // spatial_features_point  [2,128,HW]
#define O2 109707264UL    // spatial_scale_features  [2,64,HW]
#define O3 137134080UL    // point_positive_features [8000,64]
#define O4 137646080UL    // memory_positive_features[8000,64]

typedef __attribute__((ext_vector_type(8))) short bb8;
typedef __attribute__((ext_vector_type(4))) float f32x4;

__device__ __forceinline__ void fma4(float4& a, const float4& x, const float4& y) {
  a.x = fmaf(x.x, y.x, a.x);
  a.y = fmaf(x.y, y.y, a.y);
  a.z = fmaf(x.z, y.z, a.z);
  a.w = fmaf(x.w, y.w, a.w);
}

// Sorted-descending insert into top-8 registers (caller guards with sc > s[7])
__device__ __forceinline__ void insert8(float sc, int n, float s[8], int ix[8]) {
  float cs = sc; int ci = n;
#pragma unroll
  for (int i = 0; i < 8; ++i) {
    bool gt = cs > s[i];
    float ts = s[i]; int ti = ix[i];
    s[i]  = gt ? cs : ts;  ix[i] = gt ? ci : ti;
    cs    = gt ? ts : cs;  ci    = gt ? ti : ci;
  }
}

__device__ __forceinline__ void split_bf16(float x, short& h, short& l) {
  unsigned fb = __float_as_uint(x);
  unsigned hb = fb & 0xFFFF0000u;          // truncate to bf16 (hi plane)
  float lof = x - __uint_as_float(hb);     // residual
  h = (short)(hb >> 16);
  l = (short)(__float_as_uint(lof) >> 16); // bf16 of residual (lo plane)
}

// prep: fused [cvt_planes (blocks 0..511)] + [build_owner (blocks 512..543)].
// cvt arithmetic FROZEN since R2.
__global__ __launch_bounds__(256) void prep(
    const float* __restrict__ points, short* __restrict__ hi, short* __restrict__ lo,
    const int* __restrict__ indices, int* __restrict__ owner)
{
  if (blockIdx.x < 512) {
    int t = blockIdx.x * 256 + threadIdx.x;           // n4 = 131072 exactly
    float4 v = ((const float4*)points)[t];
    float x[4] = {v.x, v.y, v.z, v.w};
    short h[4], l[4];
#pragma unroll
    for (int j = 0; j < 4; ++j) split_bf16(x[j], h[j], l[j]);
    ((short4*)hi)[t] = make_short4(h[0], h[1], h[2], h[3]);
    ((short4*)lo)[t] = make_short4(l[0], l[1], l[2], l[3]);
  } else {
    int t = (blockIdx.x - 512) * 256 + threadIdx.x;
    if (t >= B_ * P_TOT) return;
    int b = (t >= P_TOT) ? 1 : 0;
    int p = t - b * P_TOT;
    atomicMax(&owner[b * HW_TOT + indices[t]], p);
  }
}

// MFMA-based top-8 for the points branch. Zero LDS — keep it that way
// (R6 lesson: merging with the LDS-using mem branch cost occupancy, +16 µs).
// FROZEN since R2 (absmax stability) — do not touch the scoring arithmetic.
__global__ __launch_bounds__(256) void topk_mfma(
    const float* __restrict__ pillars,
    const short* __restrict__ phi, const short* __restrict__ plo,
    float* __restrict__ ws_sc, int* __restrict__ ws_ix)
{
  const int tid = threadIdx.x;
  const int pt = blockIdx.x, ch = blockIdx.y, b = blockIdx.z;
  const int lane = tid & 63, wv = tid >> 6;
  const int sub = lane & 15, quad = lane >> 4;

  int prow = pt * 64 + wv * 16 + sub;
  if (prow >= P_TOT) prow = P_TOT - 1;
  const float* ap = pillars + ((size_t)(b * P_TOT) + prow) * D_;
  bb8 Ah0, Ah1, Al0, Al1;
  {
    const float4* a4 = (const float4*)(ap + quad * 8);
    const float4* b4 = (const float4*)(ap + 32 + quad * 8);
    float4 t0 = a4[0], t1 = a4[1], t2 = b4[0], t3 = b4[1];
    float av[16] = {t0.x, t0.y, t0.z, t0.w, t1.x, t1.y, t1.z, t1.w,
                    t2.x, t2.y, t2.z, t2.w, t3.x, t3.y, t3.z, t3.w};
#pragma unroll
    for (int j = 0; j < 8; ++j) {
      short h, l;
      split_bf16(av[j], h, l);     Ah0[j] = h; Al0[j] = l;
      split_bf16(av[8 + j], h, l); Ah1[j] = h; Al1[j] = l;
    }
  }

  float sv[4][8]; int iv[4][8];
#pragma unroll
  for (int r = 0; r < 4; ++r)
#pragma unroll
    for (int k = 0; k < 8; ++k) { sv[r][k] = -1e30f; iv[r][k] = 0; }

  const size_t bofs = ((size_t)(b * NP_TOT) + ch * 512) * D_;
  const short* bh = phi + bofs;
  const short* bl = plo + bofs;

#pragma unroll 2
  for (int it = 0; it < 32; ++it) {
    const int nr = it * 16 + sub;
    const short* rh = bh + nr * D_;
    const short* rl = bl + nr * D_;
    bb8 Bh0 = *(const bb8*)(rh + quad * 8);
    bb8 Bh1 = *(const bb8*)(rh + 32 + quad * 8);
    bb8 Bl0 = *(const bb8*)(rl + quad * 8);
    bb8 Bl1 = *(const bb8*)(rl + 32 + quad * 8);
    f32x4 acc = {0.f, 0.f, 0.f, 0.f};
    acc = __builtin_amdgcn_mfma_f32_16x16x32_bf16(Al0, Bh0, acc, 0, 0, 0);
    acc = __builtin_amdgcn_mfma_f32_16x16x32_bf16(Al1, Bh1, acc, 0, 0, 0);
    acc = __builtin_amdgcn_mfma_f32_16x16x32_bf16(Ah0, Bl0, acc, 0, 0, 0);
    acc = __builtin_amdgcn_mfma_f32_16x16x32_bf16(Ah1, Bl1, acc, 0, 0, 0);
    acc = __builtin_amdgcn_mfma_f32_16x16x32_bf16(Ah0, Bh0, acc, 0, 0, 0);
    acc = __builtin_amdgcn_mfma_f32_16x16x32_bf16(Ah1, Bh1, acc, 0, 0, 0);
    const int ng = ch * 512 + nr;
#pragma unroll
    for (int r = 0; r < 4; ++r) {
      float sc = acc[r];
      if (sc > sv[r][7]) insert8(sc, ng, sv[r], iv[r]);
    }
  }

  const int pbase = pt * 64 + wv * 16 + quad * 4;
#pragma unroll
  for (int r = 0; r < 4; ++r) {
    const int pg = pbase + r;
    float out_s = 0.f; int out_i = 0;
#pragma unroll
    for (int k = 0; k < 8; ++k) {
      unsigned fb = __float_as_uint(sv[r][0]);
      unsigned mk = (fb & 0x80000000u) ? ~fb : (fb | 0x80000000u);
      unsigned key = (mk & 0xFFFFFFF0u) | (unsigned)sub;
#pragma unroll
      for (int off = 1; off < 16; off <<= 1) {
        unsigned ok = (unsigned)__shfl_xor((int)key, off);
        key = key > ok ? key : ok;
      }
      const int wsub = (int)(key & 15u);
      const int wlane = (lane & 48) | wsub;
      float wsc = __shfl(sv[r][0], wlane);
      int   wix = __shfl(iv[r][0], wlane);
      if (sub == wsub) {
#pragma unroll
        for (int i2 = 0; i2 < 7; ++i2) { sv[r][i2] = sv[r][i2 + 1]; iv[r][i2] = iv[r][i2 + 1]; }
        sv[r][7] = -1e30f;
      }
      if (sub == k) { out_s = wsc; out_i = wix; }
    }
    if (sub < 8 && pg < P_TOT) {
      const size_t base = ((size_t)(b * P_TOT) + pg) * 64 + ch * 8 + sub;
      ws_sc[base] = out_s; ws_ix[base] = out_i;
    }
  }
}

// VALU top-k kernel (memory branch: 512 rows of W). FROZEN.
__global__ __launch_bounds__(256) void topk_chunk(
    const float* __restrict__ pillars, const float* __restrict__ src,
    float* __restrict__ ws_sc, int* __restrict__ ws_ix,
    int src_batch_stride, int n_tiles)
{
  __shared__ float lds_pts[64 * 64];
  __shared__ float cs_lds[32 * 65];
  __shared__ int   ci_lds[32 * 65];

  const int tid = threadIdx.x;
  const int pt = blockIdx.x, ch = blockIdx.y, b = blockIdx.z;
  const int pp = tid & 31, sg = tid >> 5;
  const int p = pt * 32 + pp;

  const float4* prow = (const float4*)(pillars + ((size_t)(b * P_TOT + p)) * D_);
  float4 pl[16];
#pragma unroll
  for (int i = 0; i < 16; ++i) pl[i] = prow[i];

  float s[8]; int ix[8];
#pragma unroll
  for (int i = 0; i < 8; ++i) { s[i] = -1e30f; ix[i] = 0; }

  const int n_base = ch * (n_tiles * 64);
  const float* srcb = src + (size_t)b * src_batch_stride;
  const int r0 = tid >> 2, seg = tid & 3;

  for (int t = 0; t < n_tiles; ++t) {
    const float4* g = (const float4*)(srcb + ((size_t)(n_base + t * 64 + r0)) * D_ + seg * 16);
    float4* dst4 = (float4*)(lds_pts + r0 * 64 + seg * 16);
    dst4[0] = g[0]; dst4[1] = g[1]; dst4[2] = g[2]; dst4[3] = g[3];
    __syncthreads();

#pragma unroll
    for (int r = 0; r < 8; ++r) {
      const int row = sg * 8 + r;
      const float4* q = (const float4*)(lds_pts + row * 64);
      float4 a0 = {0,0,0,0}, a1 = {0,0,0,0}, a2 = {0,0,0,0}, a3 = {0,0,0,0};
#pragma unroll
      for (int i = 0; i < 4; ++i) {
        fma4(a0, pl[i*4+0], q[i*4+0]);
        fma4(a1, pl[i*4+1], q[i*4+1]);
        fma4(a2, pl[i*4+2], q[i*4+2]);
        fma4(a3, pl[i*4+3], q[i*4+3]);
      }
      float sc = ((a0.x + a1.x) + (a2.x + a3.x)) + ((a0.y + a1.y) + (a2.y + a3.y))
               + ((a0.z + a1.z) + (a2.z + a3.z)) + ((a0.w + a1.w) + (a2.w + a3.w));
      int n = n_base + t * 64 + row;
      if (sc > s[7]) insert8(sc, n, s, ix);
    }
    __syncthreads();
  }

#pragma unroll
  for (int k = 0; k < 8; ++k) {
    cs_lds[pp * 65 + sg * 8 + k] = s[k];
    ci_lds[pp * 65 + sg * 8 + k] = ix[k];
  }
  __syncthreads();
  if (tid < 32) {
    float ms[8]; int mi[8];
#pragma unroll
    for (int i = 0; i < 8; ++i) { ms[i] = -1e30f; mi[i] = 0; }
    for (int k = 0; k < 64; ++k) {
      float sc = cs_lds[tid * 65 + k];
      int   ii = ci_lds[tid * 65 + k];
      if (sc > ms[7]) insert8(sc, ii, ms, mi);
    }
    const int p2 = pt * 32 + tid;
    size_t base = ((size_t)(b * P_TOT + p2)) * 64 + ch * 8;
#pragma unroll
    for (int k = 0; k < 8; ++k) { ws_sc[base + k] = ms[k]; ws_ix[base + k] = mi[k]; }
  }
}

// Merged finalize: grid.y = 0 -> points branch, 1 -> memory branch.
// Per-branch arithmetic FROZEN since R1.
__global__ __launch_bounds__(256) void finalize2(
    const float* __restrict__ points, const float* __restrict__ W,
    const float* __restrict__ ws_sc_p, const int* __restrict__ ws_ix_p,
    const float* __restrict__ ws_sc_m, const int* __restrict__ ws_ix_m,
    float* __restrict__ out_p, float* __restrict__ out_m)
{
  const int tid = threadIdx.x;
  const int lane = tid & 63, wv = tid >> 6;
  const int gp = blockIdx.x * 4 + wv;
  const int b = (gp >= P_TOT) ? 1 : 0;
  const size_t cb = (size_t)gp * 64;
  const bool mem = (blockIdx.y == 1);

  const float* ws_sc = mem ? ws_sc_m : ws_sc_p;
  const int*   ws_ix = mem ? ws_ix_m : ws_ix_p;
  const float* sb    = mem ? W : (points + (size_t)b * (NP_TOT * D_));
  float*       outp  = mem ? out_m : out_p;

  float ss = ws_sc[cb + lane];
  const int myix = ws_ix[cb + lane];

  float wsc[8]; int wix[8];
#pragma unroll
  for (int k = 0; k < 8; ++k) {
    float cv = ss; int cl = lane;
#pragma unroll
    for (int off = 32; off >= 1; off >>= 1) {
      float ov = __shfl_xor(cv, off);
      int   ol = __shfl_xor(cl, off);
      if (ov > cv || (ov == cv && ol < cl)) { cv = ov; cl = ol; }
    }
    wsc[k] = cv;
    wix[k] = __shfl(myix, cl);
    if (lane == cl) ss = -1e30f;
  }

  const float m = wsc[0];
  float e[8], Z = 0.f;
#pragma unroll
  for (int k = 0; k < 8; ++k) { e[k] = expf(wsc[k] - m); Z += e[k]; }
  const float inv = 1.0f / Z;

  float acc = 0.f;
#pragma unroll
  for (int k = 0; k < 8; ++k)
    acc = fmaf(e[k] * inv, sb[(size_t)wix[k] * 64 + lane], acc);
  outp[cb + lane] = acc;
}

// Scatter: thread owns (j4, c in [0,64)); loads owner int4 ONCE, gathers the
// 4 sources for occupied cells (pillars gather reused for both O0 and O1),
// writes 5 planes with non-temporal f32x4 stores. FROZEN since R5.
__global__ __launch_bounds__(256) void scatter5(
    const float* __restrict__ pillars, const float* __restrict__ scale,
    const float* __restrict__ pos_point, const float* __restrict__ pos_mem,
    const int* __restrict__ owner, float* __restrict__ out)
{
  const int j4 = blockIdx.x * 256 + threadIdx.x;
  if (j4 >= J4) return;
  const int c = blockIdx.y, b = blockIdx.z;

  const int4 own = ((const int4*)owner)[(size_t)b * J4 + j4];

  const size_t bo = (size_t)b * (P_TOT * D_);
  const float* sp = pillars   + bo;
  const float* sm = pos_mem   + bo;
  const float* sq = pos_point + bo;
  const float* ss = scale     + bo;

  f32x4 vp = {0.f, 0.f, 0.f, 0.f};
  f32x4 vm = vp, vq = vp, vs = vp;

  // sign bit of AND set iff all four are negative (empty) -> skip gathers
  if ((own.x & own.y & own.z & own.w) >= 0) {
    const size_t rx = (size_t)(own.x < 0 ? 0 : own.x) * 64 + c;
    const size_t ry = (size_t)(own.y < 0 ? 0 : own.y) * 64 + c;
    const size_t rz = (size_t)(own.z < 0 ? 0 : own.z) * 64 + c;
    const size_t rw = (size_t)(own.w < 0 ? 0 : own.w) * 64 + c;
    vp = (f32x4){own.x < 0 ? 0.f : sp[rx], own.y < 0 ? 0.f : sp[ry],
                 own.z < 0 ? 0.f : sp[rz], own.w < 0 ? 0.f : sp[rw]};
    vm = (f32x4){own.x < 0 ? 0.f : sm[rx], own.y < 0 ? 0.f : sm[ry],
                 own.z < 0 ? 0.f : sm[rz], own.w < 0 ? 0.f : sm[rw]};
    vq = (f32x4){own.x < 0 ? 0.f : sq[rx], own.y < 0 ? 0.f : sq[ry],
                 own.z < 0 ? 0.f : sq[rz], own.w < 0 ? 0.f : sq[rw]};
    vs = (f32x4){own.x < 0 ? 0.f : ss[rx], own.y < 0 ? 0.f : ss[ry],
                 own.z < 0 ? 0.f : ss[rz], own.w < 0 ? 0.f : ss[rw]};
  }

  f32x4* o4 = (f32x4*)out;
  __builtin_nontemporal_store(vp, o4 + (size_t)(b * 128 + c)       * J4 + j4);             // O0 pillars
  __builtin_nontemporal_store(vm, o4 + (size_t)(b * 128 + 64 + c)  * J4 + j4);             // O0 pos_mem
  __builtin_nontemporal_store(vp, o4 + 13713408UL + (size_t)(b * 128 + c)      * J4 + j4); // O1 pillars
  __builtin_nontemporal_store(vq, o4 + 13713408UL + (size_t)(b * 128 + 64 + c) * J4 + j4); // O1 pos_point
  __builtin_nontemporal_store(vs, o4 + 27426816UL + (size_t)(b * 64 + c)       * J4 + j4); // O2 scale
}

extern "C" void kernel_launch(void* const* d_in, const int* in_sizes, int n_in,
                              void* d_out, int out_size, void* d_ws, size_t ws_size,
                              hipStream_t stream) {
  const float* pillars = (const float*)d_in[0];   // [2,4000,64]
  const float* scale   = (const float*)d_in[1];   // [2,4000,64]
  const float* points  = (const float*)d_in[2];   // [2,4096,64]
  const float* W       = (const float*)d_in[3];   // [512,64]
  const int*   indices = (const int*)d_in[4];     // [2,4000]
  float* out = (float*)d_out;

  // ws layout (int units): pts cand 4x512000, owner 428544, bf16 planes
  float* ws_pts_sc = (float*)d_ws;
  int*   ws_pts_ix = (int*)d_ws + 512000;
  float* ws_mem_sc = (float*)d_ws + 1024000;
  int*   ws_mem_ix = (int*)d_ws + 1536000;
  int*   owner     = (int*)d_ws + 2048000;
  short* phi       = (short*)((int*)d_ws + 2480000);  // 524288 shorts
  short* plo       = (short*)((int*)d_ws + 2760000);  // 524288 shorts

  (void)hipMemsetAsync(owner, 0xFF, (size_t)B_ * HW_TOT * sizeof(int), stream);

  // fused cvt (512 blocks) + build_owner (32 blocks)
  prep<<<544, 256, 0, stream>>>(points, phi, plo, indices, owner);

  // point-attention branch: MFMA scoring, 8 chunks x 512 points (zero LDS)
  topk_mfma<<<dim3(63, 8, 2), 256, 0, stream>>>(pillars, phi, plo, ws_pts_sc, ws_pts_ix);

  // memory branch: VALU path, 8 chunks x 64 memory rows (W shared across batch)
  topk_chunk<<<dim3(125, 8, 2), 256, 0, stream>>>(
      pillars, W, ws_mem_sc, ws_mem_ix, 0, 1);

  // both branches' merge+softmax+gather in one launch
  finalize2<<<dim3(2000, 2), 256, 0, stream>>>(
      points, W, ws_pts_sc, ws_pts_ix, ws_mem_sc, ws_mem_ix, out + O3, out + O4);

  scatter5<<<dim3(210, 64, 2), 256, 0, stream>>>(
      pillars, scale, out + O3, out + O4, owner, out);
}

// Round 8
// 650.393 us; speedup vs baseline: 1.0793x; 1.0595x over previous
//
#include <hip/hip_runtime.h>

// Problem constants
#define B_     2
#define P_TOT  4000
#define NP_TOT 4096
#define D_     64
#define M_     512
#define HW_TOT 214272   // 496*432
#define J4     53568    // HW/4

// Output offsets (in floats, concatenated return order)
#define O0 0UL            // spatial_features        [2,128,HW]
#define O1 54853632UL     // spatial_features_point  [2,128,HW]
#define O2 109707264UL    // spatial_scale_features  [2,64,HW]
#define O3 137134080UL    // point_positive_features [8000,64]
#define O4 137646080UL    // memory_positive_features[8000,64]

typedef __attribute__((ext_vector_type(8))) short bb8;
typedef __attribute__((ext_vector_type(4))) float f32x4;

// Sorted-descending insert into top-8 registers (caller guards with sc > s[7])
__device__ __forceinline__ void insert8(float sc, int n, float s[8], int ix[8]) {
  float cs = sc; int ci = n;
#pragma unroll
  for (int i = 0; i < 8; ++i) {
    bool gt = cs > s[i];
    float ts = s[i]; int ti = ix[i];
    s[i]  = gt ? cs : ts;  ix[i] = gt ? ci : ti;
    cs    = gt ? ts : cs;  ci    = gt ? ti : ci;
  }
}

__device__ __forceinline__ void split_bf16(float x, short& h, short& l) {
  unsigned fb = __float_as_uint(x);
  unsigned hb = fb & 0xFFFF0000u;          // truncate to bf16 (hi plane)
  float lof = x - __uint_as_float(hb);     // residual
  h = (short)(hb >> 16);
  l = (short)(__float_as_uint(lof) >> 16); // bf16 of residual (lo plane)
}

// prep: fused [cvt points planes (blocks 0..511)] + [build_owner (512..543)]
//       + [cvt W planes (544..575)]. cvt arithmetic FROZEN since R2.
__global__ __launch_bounds__(256) void prep(
    const float* __restrict__ points, short* __restrict__ hi, short* __restrict__ lo,
    const int* __restrict__ indices, int* __restrict__ owner,
    const float* __restrict__ W, short* __restrict__ whi, short* __restrict__ wlo)
{
  if (blockIdx.x < 512) {
    int t = blockIdx.x * 256 + threadIdx.x;           // n4 = 131072 exactly
    float4 v = ((const float4*)points)[t];
    float x[4] = {v.x, v.y, v.z, v.w};
    short h[4], l[4];
#pragma unroll
    for (int j = 0; j < 4; ++j) split_bf16(x[j], h[j], l[j]);
    ((short4*)hi)[t] = make_short4(h[0], h[1], h[2], h[3]);
    ((short4*)lo)[t] = make_short4(l[0], l[1], l[2], l[3]);
  } else if (blockIdx.x < 544) {
    int t = (blockIdx.x - 512) * 256 + threadIdx.x;
    if (t >= B_ * P_TOT) return;
    int b = (t >= P_TOT) ? 1 : 0;
    int p = t - b * P_TOT;
    atomicMax(&owner[b * HW_TOT + indices[t]], p);
  } else {
    int t = (blockIdx.x - 544) * 256 + threadIdx.x;   // n4 = 8192 exactly
    float4 v = ((const float4*)W)[t];
    float x[4] = {v.x, v.y, v.z, v.w};
    short h[4], l[4];
#pragma unroll
    for (int j = 0; j < 4; ++j) split_bf16(x[j], h[j], l[j]);
    ((short4*)whi)[t] = make_short4(h[0], h[1], h[2], h[3]);
    ((short4*)wlo)[t] = make_short4(l[0], l[1], l[2], l[3]);
  }
}

// MFMA top-8, both branches. blockIdx.y in [0,8): points chunks of 512 (3-term
// split, FROZEN arithmetic since R2). blockIdx.y in [8,16): memory chunks of 64
// W-rows (4-term split: adds the two Al*Bl MFMAs first -> products exact in
// fp32, only accumulation-order noise ~2e-5 vs the old fp32-VALU scores).
// Zero LDS; identical register profile on both paths (R6 lesson: never merge
// paths with different resource footprints — this merge keeps them equal).
__global__ __launch_bounds__(256) void topk_mfma(
    const float* __restrict__ pillars,
    const short* __restrict__ phi, const short* __restrict__ plo,
    const short* __restrict__ whi, const short* __restrict__ wlo,
    float* __restrict__ ws_pts_sc, int* __restrict__ ws_pts_ix,
    float* __restrict__ ws_mem_sc, int* __restrict__ ws_mem_ix)
{
  const int tid = threadIdx.x;
  const int pt = blockIdx.x, chy = blockIdx.y, b = blockIdx.z;
  const bool is_mem = chy >= 8;
  const int ch = is_mem ? (chy - 8) : chy;
  const int lane = tid & 63, wv = tid >> 6;
  const int sub = lane & 15, quad = lane >> 4;

  int prow = pt * 64 + wv * 16 + sub;
  if (prow >= P_TOT) prow = P_TOT - 1;
  const float* ap = pillars + ((size_t)(b * P_TOT) + prow) * D_;
  bb8 Ah0, Ah1, Al0, Al1;
  {
    const float4* a4 = (const float4*)(ap + quad * 8);
    const float4* b4 = (const float4*)(ap + 32 + quad * 8);
    float4 t0 = a4[0], t1 = a4[1], t2 = b4[0], t3 = b4[1];
    float av[16] = {t0.x, t0.y, t0.z, t0.w, t1.x, t1.y, t1.z, t1.w,
                    t2.x, t2.y, t2.z, t2.w, t3.x, t3.y, t3.z, t3.w};
#pragma unroll
    for (int j = 0; j < 8; ++j) {
      short h, l;
      split_bf16(av[j], h, l);     Ah0[j] = h; Al0[j] = l;
      split_bf16(av[8 + j], h, l); Ah1[j] = h; Al1[j] = l;
    }
  }

  float sv[4][8]; int iv[4][8];
#pragma unroll
  for (int r = 0; r < 4; ++r)
#pragma unroll
    for (int k = 0; k < 8; ++k) { sv[r][k] = -1e30f; iv[r][k] = 0; }

  const short* bh;
  const short* bl;
  int iters, ngb;
  if (is_mem) {
    bh = whi + (size_t)(ch * 64) * D_;   // W shared across batch
    bl = wlo + (size_t)(ch * 64) * D_;
    iters = 4;  ngb = ch * 64;
  } else {
    const size_t bofs = ((size_t)(b * NP_TOT) + ch * 512) * D_;
    bh = phi + bofs;  bl = plo + bofs;
    iters = 32; ngb = ch * 512;
  }

#pragma unroll 2
  for (int it = 0; it < iters; ++it) {
    const int nr = it * 16 + sub;
    const short* rh = bh + nr * D_;
    const short* rl = bl + nr * D_;
    bb8 Bh0 = *(const bb8*)(rh + quad * 8);
    bb8 Bh1 = *(const bb8*)(rh + 32 + quad * 8);
    bb8 Bl0 = *(const bb8*)(rl + quad * 8);
    bb8 Bl1 = *(const bb8*)(rl + 32 + quad * 8);
    f32x4 acc = {0.f, 0.f, 0.f, 0.f};
    if (is_mem) {   // wave-uniform; extra lo*lo terms -> 4-term (exact products)
      acc = __builtin_amdgcn_mfma_f32_16x16x32_bf16(Al0, Bl0, acc, 0, 0, 0);
      acc = __builtin_amdgcn_mfma_f32_16x16x32_bf16(Al1, Bl1, acc, 0, 0, 0);
    }
    acc = __builtin_amdgcn_mfma_f32_16x16x32_bf16(Al0, Bh0, acc, 0, 0, 0);
    acc = __builtin_amdgcn_mfma_f32_16x16x32_bf16(Al1, Bh1, acc, 0, 0, 0);
    acc = __builtin_amdgcn_mfma_f32_16x16x32_bf16(Ah0, Bl0, acc, 0, 0, 0);
    acc = __builtin_amdgcn_mfma_f32_16x16x32_bf16(Ah1, Bl1, acc, 0, 0, 0);
    acc = __builtin_amdgcn_mfma_f32_16x16x32_bf16(Ah0, Bh0, acc, 0, 0, 0);
    acc = __builtin_amdgcn_mfma_f32_16x16x32_bf16(Ah1, Bh1, acc, 0, 0, 0);
    const int ng = ngb + nr;
#pragma unroll
    for (int r = 0; r < 4; ++r) {
      float sc = acc[r];
      if (sc > sv[r][7]) insert8(sc, ng, sv[r], iv[r]);
    }
  }

  float* osc = is_mem ? ws_mem_sc : ws_pts_sc;
  int*   oix = is_mem ? ws_mem_ix : ws_pts_ix;

  const int pbase = pt * 64 + wv * 16 + quad * 4;
#pragma unroll
  for (int r = 0; r < 4; ++r) {
    const int pg = pbase + r;
    float out_s = 0.f; int out_i = 0;
#pragma unroll
    for (int k = 0; k < 8; ++k) {
      unsigned fb = __float_as_uint(sv[r][0]);
      unsigned mk = (fb & 0x80000000u) ? ~fb : (fb | 0x80000000u);
      unsigned key = (mk & 0xFFFFFFF0u) | (unsigned)sub;
#pragma unroll
      for (int off = 1; off < 16; off <<= 1) {
        unsigned ok = (unsigned)__shfl_xor((int)key, off);
        key = key > ok ? key : ok;
      }
      const int wsub = (int)(key & 15u);
      const int wlane = (lane & 48) | wsub;
      float wsc = __shfl(sv[r][0], wlane);
      int   wix = __shfl(iv[r][0], wlane);
      if (sub == wsub) {
#pragma unroll
        for (int i2 = 0; i2 < 7; ++i2) { sv[r][i2] = sv[r][i2 + 1]; iv[r][i2] = iv[r][i2 + 1]; }
        sv[r][7] = -1e30f;
      }
      if (sub == k) { out_s = wsc; out_i = wix; }
    }
    if (sub < 8 && pg < P_TOT) {
      const size_t base = ((size_t)(b * P_TOT) + pg) * 64 + ch * 8 + sub;
      osc[base] = out_s; oix[base] = out_i;
    }
  }
}

// Merged finalize: grid.y = 0 -> points branch, 1 -> memory branch.
// Per-branch arithmetic FROZEN since R1.
__global__ __launch_bounds__(256) void finalize2(
    const float* __restrict__ points, const float* __restrict__ W,
    const float* __restrict__ ws_sc_p, const int* __restrict__ ws_ix_p,
    const float* __restrict__ ws_sc_m, const int* __restrict__ ws_ix_m,
    float* __restrict__ out_p, float* __restrict__ out_m)
{
  const int tid = threadIdx.x;
  const int lane = tid & 63, wv = tid >> 6;
  const int gp = blockIdx.x * 4 + wv;
  const int b = (gp >= P_TOT) ? 1 : 0;
  const size_t cb = (size_t)gp * 64;
  const bool mem = (blockIdx.y == 1);

  const float* ws_sc = mem ? ws_sc_m : ws_sc_p;
  const int*   ws_ix = mem ? ws_ix_m : ws_ix_p;
  const float* sb    = mem ? W : (points + (size_t)b * (NP_TOT * D_));
  float*       outp  = mem ? out_m : out_p;

  float ss = ws_sc[cb + lane];
  const int myix = ws_ix[cb + lane];

  float wsc[8]; int wix[8];
#pragma unroll
  for (int k = 0; k < 8; ++k) {
    float cv = ss; int cl = lane;
#pragma unroll
    for (int off = 32; off >= 1; off >>= 1) {
      float ov = __shfl_xor(cv, off);
      int   ol = __shfl_xor(cl, off);
      if (ov > cv || (ov == cv && ol < cl)) { cv = ov; cl = ol; }
    }
    wsc[k] = cv;
    wix[k] = __shfl(myix, cl);
    if (lane == cl) ss = -1e30f;
  }

  const float m = wsc[0];
  float e[8], Z = 0.f;
#pragma unroll
  for (int k = 0; k < 8; ++k) { e[k] = expf(wsc[k] - m); Z += e[k]; }
  const float inv = 1.0f / Z;

  float acc = 0.f;
#pragma unroll
  for (int k = 0; k < 8; ++k)
    acc = fmaf(e[k] * inv, sb[(size_t)wix[k] * 64 + lane], acc);
  outp[cb + lane] = acc;
}

// Scatter: thread owns (j4, c in [0,64)); loads owner int4 ONCE, gathers the
// 4 sources for occupied cells (pillars gather reused for both O0 and O1),
// writes 5 planes with non-temporal f32x4 stores. FROZEN since R5.
__global__ __launch_bounds__(256) void scatter5(
    const float* __restrict__ pillars, const float* __restrict__ scale,
    const float* __restrict__ pos_point, const float* __restrict__ pos_mem,
    const int* __restrict__ owner, float* __restrict__ out)
{
  const int j4 = blockIdx.x * 256 + threadIdx.x;
  if (j4 >= J4) return;
  const int c = blockIdx.y, b = blockIdx.z;

  const int4 own = ((const int4*)owner)[(size_t)b * J4 + j4];

  const size_t bo = (size_t)b * (P_TOT * D_);
  const float* sp = pillars   + bo;
  const float* sm = pos_mem   + bo;
  const float* sq = pos_point + bo;
  const float* ss = scale     + bo;

  f32x4 vp = {0.f, 0.f, 0.f, 0.f};
  f32x4 vm = vp, vq = vp, vs = vp;

  // sign bit of AND set iff all four are negative (empty) -> skip gathers
  if ((own.x & own.y & own.z & own.w) >= 0) {
    const size_t rx = (size_t)(own.x < 0 ? 0 : own.x) * 64 + c;
    const size_t ry = (size_t)(own.y < 0 ? 0 : own.y) * 64 + c;
    const size_t rz = (size_t)(own.z < 0 ? 0 : own.z) * 64 + c;
    const size_t rw = (size_t)(own.w < 0 ? 0 : own.w) * 64 + c;
    vp = (f32x4){own.x < 0 ? 0.f : sp[rx], own.y < 0 ? 0.f : sp[ry],
                 own.z < 0 ? 0.f : sp[rz], own.w < 0 ? 0.f : sp[rw]};
    vm = (f32x4){own.x < 0 ? 0.f : sm[rx], own.y < 0 ? 0.f : sm[ry],
                 own.z < 0 ? 0.f : sm[rz], own.w < 0 ? 0.f : sm[rw]};
    vq = (f32x4){own.x < 0 ? 0.f : sq[rx], own.y < 0 ? 0.f : sq[ry],
                 own.z < 0 ? 0.f : sq[rz], own.w < 0 ? 0.f : sq[rw]};
    vs = (f32x4){own.x < 0 ? 0.f : ss[rx], own.y < 0 ? 0.f : ss[ry],
                 own.z < 0 ? 0.f : ss[rz], own.w < 0 ? 0.f : ss[rw]};
  }

  f32x4* o4 = (f32x4*)out;
  __builtin_nontemporal_store(vp, o4 + (size_t)(b * 128 + c)       * J4 + j4);             // O0 pillars
  __builtin_nontemporal_store(vm, o4 + (size_t)(b * 128 + 64 + c)  * J4 + j4);             // O0 pos_mem
  __builtin_nontemporal_store(vp, o4 + 13713408UL + (size_t)(b * 128 + c)      * J4 + j4); // O1 pillars
  __builtin_nontemporal_store(vq, o4 + 13713408UL + (size_t)(b * 128 + 64 + c) * J4 + j4); // O1 pos_point
  __builtin_nontemporal_store(vs, o4 + 27426816UL + (size_t)(b * 64 + c)       * J4 + j4); // O2 scale
}

extern "C" void kernel_launch(void* const* d_in, const int* in_sizes, int n_in,
                              void* d_out, int out_size, void* d_ws, size_t ws_size,
                              hipStream_t stream) {
  const float* pillars = (const float*)d_in[0];   // [2,4000,64]
  const float* scale   = (const float*)d_in[1];   // [2,4000,64]
  const float* points  = (const float*)d_in[2];   // [2,4096,64]
  const float* W       = (const float*)d_in[3];   // [512,64]
  const int*   indices = (const int*)d_in[4];     // [2,4000]
  float* out = (float*)d_out;

  // ws layout (int units): pts cand 4x512000, owner 428544, bf16 planes
  float* ws_pts_sc = (float*)d_ws;
  int*   ws_pts_ix = (int*)d_ws + 512000;
  float* ws_mem_sc = (float*)d_ws + 1024000;
  int*   ws_mem_ix = (int*)d_ws + 1536000;
  int*   owner     = (int*)d_ws + 2048000;
  short* phi       = (short*)((int*)d_ws + 2480000);  // 524288 shorts
  short* plo       = (short*)((int*)d_ws + 2760000);  // 524288 shorts
  short* whi       = (short*)((int*)d_ws + 3030000);  // 32768 shorts
  short* wlo       = (short*)((int*)d_ws + 3050000);  // 32768 shorts

  (void)hipMemsetAsync(owner, 0xFF, (size_t)B_ * HW_TOT * sizeof(int), stream);

  // fused cvt points (512 blocks) + build_owner (32) + cvt W (32)
  prep<<<576, 256, 0, stream>>>(points, phi, plo, indices, owner, W, whi, wlo);

  // both top-k branches in one zero-LDS kernel:
  // y in [0,8) = points chunks of 512; y in [8,16) = memory chunks of 64
  topk_mfma<<<dim3(63, 16, 2), 256, 0, stream>>>(
      pillars, phi, plo, whi, wlo, ws_pts_sc, ws_pts_ix, ws_mem_sc, ws_mem_ix);

  // both branches' merge+softmax+gather in one launch
  finalize2<<<dim3(2000, 2), 256, 0, stream>>>(
      points, W, ws_pts_sc, ws_pts_ix, ws_mem_sc, ws_mem_ix, out + O3, out + O4);

  scatter5<<<dim3(210, 64, 2), 256, 0, stream>>>(
      pillars, scale, out + O3, out + O4, owner, out);
}